// Round 1
// baseline (932.697 us; speedup 1.0000x reference)
//
#include <hip/hip_runtime.h>

// CRF NLL forward loss. B=256, T=2048, K2=52 (50 labels + START=50 + STOP=51).
// Inputs: emissions f32[B,T,K2], transitions f32[K2,K2], lengths i32[B], labels i32[B,T].
// Output: scalar mean(forward_score - gold_score).

#define B_    256
#define T_    2048
#define K2_   52
#define NWAVE 4
#define CHUNK 13            // 52 prev-states / 4 waves
#define NEG_  (-10000.0f)
#define LOG2E_ 1.4426950408889634f
#define LN2_   0.6931471805599453f

__device__ __forceinline__ float rdlane(float v, int src) {
  return __uint_as_float(__builtin_amdgcn_readlane(__float_as_uint(v), src));
}

// One block per batch. 4 waves; lane = next-state (52 active of 64);
// wave w owns prev-states [w*13, w*13+13).
// Base-2 domain: everything pre-scaled by log2(e); v_exp_f32/v_log_f32 native.
// Stored alpha is renormalized each step by u[0] (offset accumulated in C),
// so exp2 args stay bounded -> no per-element max pass needed.
__launch_bounds__(256, 1)
__global__ void crf_fwd_kernel(const float* __restrict__ em,
                               const float* __restrict__ tr,
                               const int*  __restrict__ len,
                               const int*  __restrict__ lab,
                               float* __restrict__ per_b)
{
  const int b    = blockIdx.x;
  const int tid  = threadIdx.x;
  const int wave = tid >> 6;
  const int lane = tid & 63;
  const int n    = (lane < K2_) ? lane : (K2_ - 1);  // clamped next-state (lanes 52..63 inert)
  const int L    = len[b];
  const float* emb = em + (size_t)b * (T_ * K2_);

  __shared__ float part[2][NWAVE][64];   // double-buffered partial sums -> 1 barrier/step
  __shared__ float s_g[NWAVE];

  // per-lane transition chunk: tr2[next=n][p0+p], base-2 scaled (13 VGPRs)
  const int p0 = wave * CHUNK;
  float trc[CHUNK];
#pragma unroll
  for (int p = 0; p < CHUNK; ++p)
    trc[p] = tr[n * K2_ + p0 + p] * LOG2E_;

  // stored alpha (lane = state). a[START]=0, else -1e4. C = running offset.
  float a = (lane == K2_ - 2) ? 0.0f : NEG_;
  float C = 0.0f;

  // wave's broadcast copy of alpha for its prev chunk (SGPRs via readlane)
  float ap[CHUNK];
#pragma unroll
  for (int p = 0; p < CHUNK; ++p) ap[p] = rdlane(a, p0 + p);

  // emissions prefetch pipeline (row t in em0, t+1 in em1)
  float em0 = emb[0 * K2_ + n];
  float em1 = emb[1 * K2_ + n];

  for (int t = 0; t < L; ++t) {
    int tpf = t + 2; if (tpf > T_ - 1) tpf = T_ - 1;
    float em2 = emb[tpf * K2_ + n];      // prefetch row t+2

    // partial_n = sum over this wave's 13 prevs of 2^(tr2 + a)
    float acc0 = 0.0f, acc1 = 0.0f, acc2 = 0.0f, acc3 = 0.0f;
#pragma unroll
    for (int p = 0; p < 12; p += 4) {
      acc0 += __builtin_amdgcn_exp2f(trc[p + 0] + ap[p + 0]);
      acc1 += __builtin_amdgcn_exp2f(trc[p + 1] + ap[p + 1]);
      acc2 += __builtin_amdgcn_exp2f(trc[p + 2] + ap[p + 2]);
      acc3 += __builtin_amdgcn_exp2f(trc[p + 3] + ap[p + 3]);
    }
    acc0 += __builtin_amdgcn_exp2f(trc[12] + ap[12]);
    float partial = (acc0 + acc1) + (acc2 + acc3);

    const int buf = t & 1;
    part[buf][wave][lane] = partial;
    __syncthreads();
    float tot = (part[buf][0][lane] + part[buf][1][lane])
              + (part[buf][2][lane] + part[buf][3][lane]);

    // u = log2(sum) + emissions (base-2); renormalize by u[0]
    float u = __builtin_amdgcn_logf(tot) + em0 * LOG2E_;
    float m = rdlane(u, 0);
    a = u - m;
    C += m;
#pragma unroll
    for (int p = 0; p < CHUNK; ++p) ap[p] = rdlane(a, p0 + p);

    em0 = em1; em1 = em2;
  }

  // ---- terminal: forward = ln2 * (C + log2 sum_p 2^(a[p] + tr2[STOP][p])) ----
  float fwd = 0.0f;
  if (wave == 0) {
    float xs = (lane < K2_) ? (a + tr[(K2_ - 1) * K2_ + n] * LOG2E_) : NEG_;
    float e = __builtin_amdgcn_exp2f(xs);
#pragma unroll
    for (int off = 32; off >= 1; off >>= 1) e += __shfl_xor(e, off, 64);
    fwd = (C + __builtin_amdgcn_logf(e)) * LN2_;
  }

  // ---- gold score (raw, not base-2): emissions along label path + transitions ----
  float g = 0.0f;
  const int* labb = lab + b * T_;
  for (int t = tid; t < L; t += 256) {
    int l1 = labb[t];
    int l0 = (t == 0) ? (K2_ - 2) : labb[t - 1];
    g += emb[t * K2_ + l1] + tr[l1 * K2_ + l0];
  }
  if (tid == 0) g += tr[(K2_ - 1) * K2_ + labb[L - 1]];  // STOP <- last label
#pragma unroll
  for (int off = 32; off >= 1; off >>= 1) g += __shfl_xor(g, off, 64);
  if (lane == 0) s_g[wave] = g;
  __syncthreads();
  if (tid == 0) {
    float gg = (s_g[0] + s_g[1]) + (s_g[2] + s_g[3]);
    per_b[b] = fwd - gg;
  }
}

__global__ void reduce_mean_kernel(const float* __restrict__ per_b,
                                   float* __restrict__ out)
{
  const int tid = threadIdx.x;  // 256
  float v = per_b[tid];
#pragma unroll
  for (int off = 32; off >= 1; off >>= 1) v += __shfl_xor(v, off, 64);
  __shared__ float s[4];
  if ((tid & 63) == 0) s[tid >> 6] = v;
  __syncthreads();
  if (tid == 0) out[0] = ((s[0] + s[1]) + (s[2] + s[3])) * (1.0f / (float)B_);
}

extern "C" void kernel_launch(void* const* d_in, const int* in_sizes, int n_in,
                              void* d_out, int out_size, void* d_ws, size_t ws_size,
                              hipStream_t stream) {
  const float* em  = (const float*)d_in[0];   // [B,T,K2] f32
  const float* tr  = (const float*)d_in[1];   // [K2,K2]  f32
  const int*   len = (const int*)d_in[2];     // [B] i32
  const int*   lab = (const int*)d_in[3];     // [B,T] i32
  float* out = (float*)d_out;
  float* ws  = (float*)d_ws;                  // 256 floats of per-batch scores

  crf_fwd_kernel<<<B_, 256, 0, stream>>>(em, tr, len, lab, ws);
  reduce_mean_kernel<<<1, 256, 0, stream>>>(ws, out);
}